// Round 6
// baseline (17.898 us; speedup 1.0000x reference)
//
#include <hip/hip_runtime.h>
#include <math.h>

typedef float f2v __attribute__((ext_vector_type(2)));

#define BATCH 4096
#define NPAIRF 2016.0f

__device__ __forceinline__ f2v relu2(f2v t) {
    t.x = fmaxf(t.x, 0.0f);
    t.y = fmaxf(t.y, 0.0f);
    return t;
}

// DPP-based wave64 sum (VALU pipe, no DS traffic). Total lands in lane 63.
template <int CTRL>
__device__ __forceinline__ float dpp_add(float x) {
    int y = __builtin_amdgcn_update_dpp(0, __builtin_bit_cast(int, x), CTRL, 0xf, 0xf, true);
    return x + __builtin_bit_cast(float, y);
}
__device__ __forceinline__ float wave_sum63(float x) {
    x = dpp_add<0x111>(x);  // row_shr:1
    x = dpp_add<0x112>(x);  // row_shr:2
    x = dpp_add<0x114>(x);  // row_shr:4
    x = dpp_add<0x118>(x);  // row_shr:8  -> lane 15/31/47/63 hold 16-lane sums
    x = dpp_add<0x142>(x);  // row_bcast:15 -> lane31 = 0..31, lane63 = 32..63
    x = dpp_add<0x143>(x);  // row_bcast:31 -> lane63 = 0..63
    return x;
}

__global__ __launch_bounds__(256, 8) void akan_kernel(
    const float* __restrict__ x,
    const float* __restrict__ phi_W1, const float* __restrict__ phi_b1,
    const float* __restrict__ phi_W2, const float* __restrict__ phi_b2,
    const float* __restrict__ attn_W, const float* __restrict__ attn_b,
    const float* __restrict__ psi_W1, const float* __restrict__ psi_b1,
    const float* __restrict__ psi_W2, const float* __restrict__ psi_b2,
    float* __restrict__ out)
{
    // rows[sample][region][row][quad]; region 0 = v, region 1 = u (48 B rows)
    __shared__ __align__(16) float4 rows[2][2][64][3];
    __shared__ float poS[2][2][8];

    const int lane = threadIdx.x & 63;
    const int wv   = threadIdx.x >> 6;
    const int s    = wv >> 1;    // sample slot in block
    const int half = wv & 1;     // 0: d=1..15 (+d=32 half), 1: d=16..31
    const int b    = blockIdx.x * 2 + s;

    // ---- phi: per-feature scalar MLP (input dim 1) ----
    const float xv = x[b * 64 + lane];
    float phi_out[5];
    #pragma unroll
    for (int o = 0; o < 5; ++o) phi_out[o] = phi_b2[o];
    #pragma unroll
    for (int k = 0; k < 10; ++k) {
        const float h = fmaxf(fmaf(xv, phi_W1[k], phi_b1[k]), 0.0f);
        #pragma unroll
        for (int o = 0; o < 5; ++o) phi_out[o] = fmaf(h, phi_W2[k * 5 + o], phi_out[o]);
    }

    // ---- attention softmax over the 64 features (shift-invariant, scores tiny) ----
    float score = attn_b[0];
    #pragma unroll
    for (int o = 0; o < 5; ++o) score = fmaf(phi_out[o], attn_W[o], score);
    const float e = __expf(score);
    const float t63 = wave_sum63(e);
    const float ssum = __builtin_bit_cast(float,
        __builtin_amdgcn_readlane(__builtin_bit_cast(int, t63), 63));
    const float wgt = e * __builtin_amdgcn_rcpf(ssum);

    // ---- psi layer-1 split: u (rows 0..4 of psi_W1, +b1) / v (rows 5..9), packed ----
    float w[5];
    #pragma unroll
    for (int o = 0; o < 5; ++o) w[o] = phi_out[o] * wgt;

    f2v U[5], V[5];
    #pragma unroll
    for (int j = 0; j < 5; ++j) {
        const int h0 = 2 * j, h1 = 2 * j + 1;
        float u0 = psi_b1[h0], u1 = psi_b1[h1], v0 = 0.0f, v1 = 0.0f;
        #pragma unroll
        for (int o = 0; o < 5; ++o) {
            u0 = fmaf(w[o], psi_W1[o * 10 + h0], u0);
            u1 = fmaf(w[o], psi_W1[o * 10 + h1], u1);
            v0 = fmaf(w[o], psi_W1[(5 + o) * 10 + h0], v0);
            v1 = fmaf(w[o], psi_W1[(5 + o) * 10 + h1], v1);
        }
        U[j] = (f2v){u0, u1};
        V[j] = (f2v){v0, v1};
    }

    // ---- stage this sample's rows: half0 writes u, half1 writes v ----
    if (half) {
        rows[s][0][lane][0] = make_float4(V[0].x, V[0].y, V[1].x, V[1].y);
        rows[s][0][lane][1] = make_float4(V[2].x, V[2].y, V[3].x, V[3].y);
        *(float2*)&rows[s][0][lane][2] = make_float2(V[4].x, V[4].y);
    } else {
        rows[s][1][lane][0] = make_float4(U[0].x, U[0].y, U[1].x, U[1].y);
        rows[s][1][lane][1] = make_float4(U[2].x, U[2].y, U[3].x, U[3].y);
        *(float2*)&rows[s][1][lane][2] = make_float2(U[4].x, U[4].y);
    }
    __syncthreads();

    // ---- pair loop over this wave's d-range (wrap-around, all lanes active) ----
    f2v S[5];
    #pragma unroll
    for (int j = 0; j < 5; ++j) S[j] = (f2v){0.0f, 0.0f};

    const int dlo   = half ? 16 : 1;
    const int niter = half ? 16 : 15;
    #pragma unroll 4
    for (int t = 0; t < niter; ++t) {
        const int d  = dlo + t;
        const int pl = lane + d;
        const int wr = pl >> 6;           // 1 = wrapped -> remote is u-region
        const int m  = pl & 63;
        const float4* rp = rows[s][wr][m];
        const float4 ra = rp[0];
        const float4 rb = rp[1];
        const float2 rc = *(const float2*)(rp + 2);
        const bool uplocal = (wr == 0);
        const f2v R[5] = {{ra.x, ra.y}, {ra.z, ra.w}, {rb.x, rb.y}, {rb.z, rb.w}, {rc.x, rc.y}};
        #pragma unroll
        for (int j = 0; j < 5; ++j) {
            const f2v L = uplocal ? U[j] : V[j];
            S[j] += relu2(L + R[j]);
        }
    }
    if (!half && lane < 32) {   // d = 32: pair (lane, lane+32), counted once
        const float4* rp = rows[s][0][lane + 32];
        const float4 ra = rp[0];
        const float4 rb = rp[1];
        const float2 rc = *(const float2*)(rp + 2);
        const f2v R[5] = {{ra.x, ra.y}, {ra.z, ra.w}, {rb.x, rb.y}, {rb.z, rb.w}, {rc.x, rc.y}};
        #pragma unroll
        for (int j = 0; j < 5; ++j) S[j] += relu2(U[j] + R[j]);
    }

    // ---- psi layer-2 first (linear), then DPP-reduce 5 values (VALU pipe) ----
    float sv[10];
    #pragma unroll
    for (int j = 0; j < 5; ++j) { sv[2 * j] = S[j].x; sv[2 * j + 1] = S[j].y; }

    float po[5];
    #pragma unroll
    for (int o = 0; o < 5; ++o) {
        float acc = 0.0f;
        #pragma unroll
        for (int hh = 0; hh < 10; ++hh)
            acc = fmaf(sv[hh], psi_W2[hh * 5 + o], acc);
        po[o] = wave_sum63(acc);
    }

    if (lane == 63) {
        *(float4*)&poS[s][half][0] = make_float4(po[0], po[1], po[2], po[3]);
        poS[s][half][4] = po[4];
    }
    __syncthreads();

    // ---- combine the two halves, add pair-count * psi_b2, store ----
    if (!half && lane < 5) {
        out[b * 5 + lane] = poS[s][0][lane] + poS[s][1][lane] + NPAIRF * psi_b2[lane];
    }
}

extern "C" void kernel_launch(void* const* d_in, const int* in_sizes, int n_in,
                              void* d_out, int out_size, void* d_ws, size_t ws_size,
                              hipStream_t stream) {
    const float* x      = (const float*)d_in[0];
    const float* phi_W1 = (const float*)d_in[1];
    const float* phi_b1 = (const float*)d_in[2];
    const float* phi_W2 = (const float*)d_in[3];
    const float* phi_b2 = (const float*)d_in[4];
    const float* attn_W = (const float*)d_in[5];
    const float* attn_b = (const float*)d_in[6];
    const float* psi_W1 = (const float*)d_in[7];
    const float* psi_b1 = (const float*)d_in[8];
    const float* psi_W2 = (const float*)d_in[9];
    const float* psi_b2 = (const float*)d_in[10];
    float* outp = (float*)d_out;

    dim3 grid(BATCH / 2);   // 2 samples per block, 2 waves per sample
    dim3 block(256);
    akan_kernel<<<grid, block, 0, stream>>>(x, phi_W1, phi_b1, phi_W2, phi_b2,
                                            attn_W, attn_b, psi_W1, psi_b1,
                                            psi_W2, psi_b2, outp);
}